// Round 10
// baseline (160.026 us; speedup 1.0000x reference)
//
#include <hip/hip_runtime.h>

#define PHN 7
#define PWN 7
#define NB 49
#define SSCALE 0.0625f
#define CC 256
#define HH 200
#define WW 200
#define HWSZ (HH * WW)

#define CPG 8                     // channels per WAVE (sequential passes)
#define NSLOT 11                  // 16B slots per row: 11*16 = 176 B = row pitch
#define PITCHF 44                 // floats per tap row
#define REG_F 1280                // floats per buffer: 5 chunks x 1024 B
#define MAXELEM 307               // last valid (placed-row,slot) elem: 28*11-1

// No-VGPR-destination staging load: allocator can't serialize it; LDS dest =
// uniform base + lane*16 (linear), rows pack at exactly 176 B.
__device__ __forceinline__ void gload_lds16(const float* g, float* l) {
    __builtin_amdgcn_global_load_lds(
        (const __attribute__((address_space(1))) void*)g,
        (__attribute__((address_space(3))) void*)l, 16, 0, 0);
}

// Counted waits are safe here: every gload_lds is FULL-WAVE and unpredicated,
// so the per-wave vmcnt FIFO depth is statically known (5 per channel).
#define WAITV(n) do { asm volatile("s_waitcnt vmcnt(" #n ")" ::: "memory"); \
                      __builtin_amdgcn_sched_barrier(0); } while (0)
#define LGKM0 do { asm volatile("s_waitcnt lgkmcnt(0)" ::: "memory"); \
                   __builtin_amdgcn_sched_barrier(0); } while (0)

__global__ __launch_bounds__(256, 4) void roi_align_v17(
    const float* __restrict__ features, const float* __restrict__ rois,
    float* __restrict__ out, int N)
{
    __shared__ float lds[4 * 2 * REG_F];   // 40,960 B -> exactly 4 blocks/CU

    // grid(8, N/4, 4): blockIdx.x IS the xcd (linear round-robin).
    // Each XCD sweeps all roi-quads of one 8-channel slab (2.56 MB < L2).
    const int xcd = blockIdx.x;
    const int cg  = blockIdx.z * 8 + xcd;            // 0..31
    const int c0  = cg * CPG;

    const int wid  = __builtin_amdgcn_readfirstlane(threadIdx.x >> 6);
    const int lane = threadIdx.x & 63;

    int roi = blockIdx.y * 4 + wid;                  // wave owns ONE roi
    if (roi > N - 1) roi = N - 1;

    float* tb0 = &lds[wid * 2 * REG_F];              // double-buffered region

    // ---- roi decode: uniform per wave ----
    const float* r = rois + (size_t)roi * 5;
    const int   b  = (int)r[0];
    const float x1 = r[1] * SSCALE, y1 = r[2] * SSCALE;
    const float x2 = r[3] * SSCALE, y2 = r[4] * SSCALE;
    const float bw = fmaxf(x2 - x1, 1.f) * (1.f / PWN);
    const float bh = fmaxf(y2 - y1, 1.f) * (1.f / PHN);
    const int col0a = min((int)fmaxf(x1 + 0.25f * bw, 0.f), WW - 1) & ~3;

    const float* fb = features + (size_t)(b * CC + c0) * HWSZ;

    // ---- hoisted per-lane source offsets (once per wave, reused x8) ----
    // Placed row q holds ACTUAL tap-row r = (q%7)*4 + q/7. The 7 rows read
    // concurrently (fixed iy,tap) then sit at placed rows c*7+ph -> bank
    // bases 12*ph mod 32, all distinct -> zero structural conflicts.
    int voff[5];
    #pragma unroll
    for (int k = 0; k < 5; ++k) {
        int e = k * 64 + lane; if (e > MAXELEM) e = MAXELEM;
        int q  = e / NSLOT;                  // placed row 0..27 (magic-mul)
        int sl = e - q * NSLOT;
        int qm = q / 7;                      // 0..3
        int rr = (q - qm * 7) * 4 + qm;      // actual tap-row (perm inverse)
        int s = rr >> 1, tap = rr & 1;
        float yb = (float)(s >> 1) + ((s & 1) ? 0.75f : 0.25f);
        float y  = y1 + yb * bh;
        float cy = fmaxf(y, 0.f);
        int   yl = min((int)cy, HH - 1);
        int   gr = min(yl + tap, HH - 1);    // hi-row clamp: dup row, wts ok
        int   gc = min(col0a + (sl << 2), WW - 4);
        voff[k] = (gr * WW + gc) * 4;        // byte offset within channel
    }

    // ---- bin weights: once per wave (lane = bin) ----
    const int phl = lane / PWN;
    const int pwl = lane - phl * PWN;
    float swx0[2], swx1[2], swy0[2], swy1[2]; int soA[2];
    #pragma unroll
    for (int i = 0; i < 2; ++i) {
        float sf = i ? 0.75f : 0.25f;
        float x  = x1 + ((float)pwl + sf) * bw;
        bool  vx = (x >= -1.f) && (x <= (float)WW);
        float cx = fmaxf(x, 0.f);
        int   xl = min((int)cx, WW - 1);
        float fx = (xl >= WW - 1) ? 0.f : (cx - (float)xl);
        swx0[i] = vx ? (1.f - fx) : 0.f;
        swx1[i] = vx ? fx : 0.f;
        soA[i]  = xl - col0a;                // 0..41 (+1 tap <= 43 < 44)
        float yp = y1 + ((float)phl + sf) * bh;
        bool  vy = (yp >= -1.f) && (yp <= (float)HH);
        float cyy = fmaxf(yp, 0.f);
        int   yll = min((int)cyy, HH - 1);
        float fyy = cyy - (float)yll;
        swy0[i] = vy ? (1.f - fyy) : 0.f;
        swy1[i] = vy ? fyy : 0.f;
    }

#define ISSUE(CH, BUF) { const char* f_ = (const char*)(fb + (size_t)(CH) * HWSZ); \
    _Pragma("unroll") for (int k_ = 0; k_ < 5; ++k_) \
        gload_lds16((const float*)(f_ + voff[k_]), (BUF) + k_ * 256); }

    // ---- prologue: two channels in flight ----
    ISSUE(0, tb0);
    ISSUE(1, tb0 + REG_F);

    // ---- 8 channel passes: compute[ch] overlaps loads[ch+1] in flight ----
    #pragma unroll
    for (int ch = 0; ch < CPG; ++ch) {
        float* tb = tb0 + (ch & 1) * REG_F;          // static under unroll

        if (ch < CPG - 1) WAITV(5); else WAITV(0);   // ch's 5 landed; ch+1 flying

        float acc = 0.f;
        if (lane < NB) {
            #pragma unroll
            for (int iy = 0; iy < 2; ++iy) {
                // placed rows 14iy+phl (lo-tap) and +7 (hi-tap)
                const float* plo = tb + (14 * iy + phl) * PITCHF;
                const float* phi = plo + 7 * PITCHF;
                float rlo = swx0[0] * plo[soA[0]] + swx1[0] * plo[soA[0] + 1]
                          + swx0[1] * plo[soA[1]] + swx1[1] * plo[soA[1] + 1];
                float rhi = swx0[0] * phi[soA[0]] + swx1[0] * phi[soA[0] + 1]
                          + swx0[1] * phi[soA[1]] + swx1[1] * phi[soA[1] + 1];
                acc += swy0[iy] * rlo + swy1[iy] * rhi;
            }
        }

        if (lane < NB)
            out[(size_t)(roi * CC + c0 + ch) * NB + lane] = acc * 0.25f;

        if (ch < CPG - 2) {                  // refill the buffer just consumed
            LGKM0;                           // our ds_reads fully drained
            ISSUE(ch + 2, tb);
        }
    }
}

extern "C" void kernel_launch(void* const* d_in, const int* in_sizes, int n_in,
                              void* d_out, int out_size, void* d_ws, size_t ws_size,
                              hipStream_t stream) {
    const float* features = (const float*)d_in[0];
    const float* rois     = (const float*)d_in[1];
    float*       out      = (float*)d_out;

    int N = in_sizes[1] / 5;                 // 512 rois
    int quads = (N + 3) / 4;                 // 128 roi-quads (1 roi per wave)

    dim3 grid(8, quads, CC / CPG / 8);       // (xcd, roi-quad, cgroup-phase)
    roi_align_v17<<<grid, 256, 0, stream>>>(features, rois, out, N);
}

// Round 11
// 149.018 us; speedup vs baseline: 1.0739x; 1.0739x over previous
//
#include <hip/hip_runtime.h>

#define PHN 7
#define PWN 7
#define NB 49
#define SSCALE 0.0625f
#define CC 256
#define HH 200
#define WW 200
#define HWSZ (HH * WW)

#define CPG 8                     // channels per WAVE (sequential passes)
#define REG_F 1280                // stage region: 5 chunks x 1024 B (worst case)
#define RES_F 392                 // result tile: 8 ch x 49 bins

typedef float f4 __attribute__((ext_vector_type(4)));

// No-VGPR-dest staging load; LDS dest = uniform base + lane*16 (linear).
__device__ __forceinline__ void gload_lds16(const float* g, float* l) {
    __builtin_amdgcn_global_load_lds(
        (const __attribute__((address_space(1))) void*)g,
        (__attribute__((address_space(3))) void*)l, 16, 0, 0);
}

#define WAITV0 do { asm volatile("s_waitcnt vmcnt(0)" ::: "memory");      \
                    __builtin_amdgcn_sched_barrier(0); } while (0)
#define LGKM0  do { asm volatile("s_waitcnt lgkmcnt(0)" ::: "memory");    \
                    __builtin_amdgcn_sched_barrier(0); } while (0)

__global__ __launch_bounds__(256, 6) void roi_align_v18(
    const float* __restrict__ features, const float* __restrict__ rois,
    float* __restrict__ out, int N)
{
    __shared__ __align__(16) float lds[4 * REG_F];   // 20,480 B
    __shared__ __align__(16) float res[4 * RES_F];   // + 6,272 B = 26,752 -> 6 blk/CU

    // grid(8, N/4, 4): blockIdx.x IS the xcd; each XCD sweeps one 8-channel
    // slab (2.56 MB < 4 MB L2) across all rois before the next.
    const int xcd = blockIdx.x;
    const int cg  = blockIdx.z * 8 + xcd;
    const int c0  = cg * CPG;

    const int wid  = __builtin_amdgcn_readfirstlane(threadIdx.x >> 6);
    const int lane = threadIdx.x & 63;

    int roi = blockIdx.y * 4 + wid;                  // wave owns ONE roi
    if (roi > N - 1) roi = N - 1;

    float* tb = &lds[wid * REG_F];                   // wave-private stage
    float* rb = &res[wid * RES_F];                   // wave-private results

    // ---- roi decode (wave-uniform) ----
    const float* r = rois + (size_t)roi * 5;
    const int   b  = (int)r[0];
    const float x1 = r[1] * SSCALE, y1 = r[2] * SSCALE;
    const float x2 = r[3] * SSCALE, y2 = r[4] * SSCALE;
    const float bw = fmaxf(x2 - x1, 1.f) * (1.f / PWN);
    const float bh = fmaxf(y2 - y1, 1.f) * (1.f / PHN);

    // ---- dynamic window extents (the lane-request reduction) ----
    const int col0  = min((int)fmaxf(x1 + 0.25f * bw, 0.f), WW - 1);
    const int col0a = col0 & ~3;
    const int xlmax = min((int)fmaxf(x1 + 6.75f * bw, 0.f), WW - 1);  // x monotone
    const int n_sl  = (xlmax + 2 - col0a + 3) >> 2;  // 1..11 slots/row
    const int pf    = n_sl << 2;                     // floats per staged row

    const int rlo   = min((int)fmaxf(y1 + 0.25f * bh, 0.f), HH - 1);  // y monotone
    const int ylast = min((int)fmaxf(y1 + 6.75f * bh, 0.f), HH - 1);
    const int spanR = ylast + 2 - rlo;               // contiguous rows incl +1 tap
    const bool modeA = (spanR <= 28);                // dedup'd contiguous staging
    const int R     = modeA ? spanR : 28;            // else 28 sample-rows (v16)
    const int nelem = R * n_sl;                      // <= 308 16B elements
    const int nch   = (nelem + 63) >> 6;             // 1..5 chunks
    const unsigned magic = 65536u / (unsigned)n_sl + 1u;  // exact for e<=307

    const float* fb = features + (size_t)(b * CC + c0) * HWSZ;

    // ---- hoisted per-lane source offsets (once per wave, reused x8) ----
    int voff[5];
    #pragma unroll
    for (int k = 0; k < 5; ++k) if (k < nch) {       // uniform guard
        unsigned e = (unsigned)(k * 64 + lane);
        if ((int)e >= nelem) e = (unsigned)(nelem - 1);   // keep full exec
        int row = (int)((e * magic) >> 16);          // e / n_sl
        int sl  = (int)e - row * n_sl;
        int gr;
        if (modeA) {
            gr = min(rlo + row, HH - 1);             // contiguous range
        } else {
            int s = row >> 1, tap = row & 1;         // sample-indexed (v16)
            float yb = (float)(s >> 1) + ((s & 1) ? 0.75f : 0.25f);
            float y  = y1 + yb * bh;
            int  yl  = min((int)fmaxf(y, 0.f), HH - 1);
            gr = min(yl + tap, HH - 1);              // clamp dup-row, wts ok
        }
        int gc = min(col0a + (sl << 2), WW - 4);     // clamped slots unneeded
        voff[k] = (gr * WW + gc) * 4;
    }

    // ---- bin weights + LDS row pointers (once; constant across channels) ----
    const int phl = lane / PWN;
    const int pwl = lane - phl * PWN;
    float swx0[2], swx1[2], swy0[2], swy1[2]; int soA[2];
    const float *plo[2], *phi[2];
    #pragma unroll
    for (int i = 0; i < 2; ++i) {
        float sf = i ? 0.75f : 0.25f;
        float x  = x1 + ((float)pwl + sf) * bw;
        bool  vx = (x >= -1.f) && (x <= (float)WW);
        float cx = fmaxf(x, 0.f);
        int   xl = min((int)cx, WW - 1);
        float fx = (xl >= WW - 1) ? 0.f : (cx - (float)xl);
        swx0[i] = vx ? (1.f - fx) : 0.f;
        swx1[i] = vx ? fx : 0.f;                     // right edge: +1 weight 0
        soA[i]  = xl - col0a;                        // within staged width
        float yp = y1 + ((float)phl + sf) * bh;
        bool  vy = (yp >= -1.f) && (yp <= (float)HH);
        float cy = fmaxf(yp, 0.f);
        int   yll = min((int)cy, HH - 1);
        float fy = cy - (float)yll;                  // dup-row at clamp: sum ok
        swy0[i] = vy ? (1.f - fy) : 0.f;
        swy1[i] = vy ? fy : 0.f;
        int ra, rbz;
        if (modeA) { ra = yll - rlo; rbz = min(yll + 1, HH - 1) - rlo; }
        else       { ra = 4 * phl + 2 * i; rbz = ra + 1; }
        plo[i] = tb + ra  * pf;                      // pointers fixed for all 8 ch
        phi[i] = tb + rbz * pf;
    }

    // ---- prologue: stage channel 0 (nch instrs instead of 5) ----
    #pragma unroll
    for (int k = 0; k < 5; ++k) if (k < nch)
        gload_lds16((const float*)((const char*)fb + voff[k]), tb + k * 256);

    // ---- 8 channel passes ----
    #pragma unroll
    for (int ch = 0; ch < CPG; ++ch) {
        WAITV0;                                      // staged rows in LDS

        float acc = 0.f;
        if (lane < NB) {
            #pragma unroll
            for (int i = 0; i < 2; ++i) {
                float rl = swx0[0] * plo[i][soA[0]] + swx1[0] * plo[i][soA[0] + 1]
                         + swx0[1] * plo[i][soA[1]] + swx1[1] * plo[i][soA[1] + 1];
                float rh = swx0[0] * phi[i][soA[0]] + swx1[0] * phi[i][soA[0] + 1]
                         + swx0[1] * phi[i][soA[1]] + swx1[1] * phi[i][soA[1] + 1];
                acc += swy0[i] * rl + swy1[i] * rh;
            }
        }

        LGKM0;                                       // reads drained: overwrite ok
        if (ch < CPG - 1) {
            const char* fn = (const char*)(fb + (size_t)(ch + 1) * HWSZ);
            #pragma unroll
            for (int k = 0; k < 5; ++k) if (k < nch)
                gload_lds16((const float*)(fn + voff[k]), tb + k * 256);
        }
        if (lane < NB) rb[ch * NB + lane] = acc * 0.25f;   // ds_write result
    }

    // ---- batched output: 2 dwordx4 stores (98 lane-reqs vs 392 dwords) ----
    float* ob = out + ((size_t)roi * CC + c0) * NB;  // 16B-aligned (c0 mult 8)
    #pragma unroll
    for (int j = 0; j < 2; ++j) {
        int e = j * 64 + lane;
        if (e < RES_F / 4)
            *(f4*)(ob + (e << 2)) = *(const f4*)&rb[e << 2];
    }
}

extern "C" void kernel_launch(void* const* d_in, const int* in_sizes, int n_in,
                              void* d_out, int out_size, void* d_ws, size_t ws_size,
                              hipStream_t stream) {
    const float* features = (const float*)d_in[0];
    const float* rois     = (const float*)d_in[1];
    float*       out      = (float*)d_out;

    int N = in_sizes[1] / 5;                 // 512 rois
    int quads = (N + 3) / 4;                 // 128 roi-quads (1 roi per wave)

    dim3 grid(8, quads, CC / CPG / 8);       // (xcd, roi-quad, cgroup-phase)
    roi_align_v18<<<grid, 256, 0, stream>>>(features, rois, out, N);
}